// Round 8
// baseline (247.713 us; speedup 1.0000x reference)
//
#include <hip/hip_runtime.h>

// incepLayer, float32 in/out. out = concat([h, f1, f2, f3]); f_k are alpha-
// mixes of P^k h, P = weighted segment_sum over edges, e = d[src]*d[dst].
//
// R6 (R7 = compile fix: NT builtins need clang ext_vector types, not HIP
// float2): chunked L2-resident gather tables, CACHED bucket loads,
// zero-shuffle issue structure.
//  - Evidence: unchunked gather pinned at ~3.6 TB/s across 3 issue shapes
//    (212-226 us) -> L3 random-service limit. R2/R4 proved chunk residency
//    collapses table FETCH; their regression was NT bucket loads (FETCH
//    showed buckets fetched from HBM every sweep, ~900cy in the chain).
//  - tab[c][node][16 u32]: chunk c = 32 dims, 2.56 MB < 4 MB per-XCD L2.
//    blockIdx%8 in {2c,2c+1} -> XCD pair owns chunk c end-to-end (cvt
//    writes, agg reads+writes, agg3 reads) across all passes.
//  - Wave = 4 nodes x 16 lanes. Subgroup n reads its node's bucket row via
//    broadcast u32x4 (CACHED, L1-hot, 4 edges/load); lane t gathers 4 B of
//    each edge row (16x4B = 64 B row, coalesced); lane owns dims {2t,2t+1}
//    -> no shfl, no LDS, no reduce; acc = 2 VGPRs -> max occupancy.
//  - NT only on pure streams (src/dst, h reads, final out stores).
// Numerics unchanged vs verified rounds: f16 weights, bf16 rows, f32 acc.

#define NN  40000
#define NE  640000
#define CAP 64   // in-degree ~ Poisson(16); P(>64) ~ 1e-17
#define NCH 4    // dim chunks (32 dims each)
#define CWU 16   // u32 words per chunk-row (2 dims per u32)

typedef unsigned int uint;
typedef unsigned short ushort;
typedef uint  u32x4 __attribute__((ext_vector_type(4)));
typedef float f32x2 __attribute__((ext_vector_type(2)));

__device__ inline ushort f2h(float f) {
    _Float16 h = (_Float16)f;
    return *(ushort*)&h;
}
__device__ inline float h2f(ushort u) {
    _Float16 h = *(_Float16*)&u;
    return (float)h;
}
__device__ inline ushort f2bf(float f) {  // round-to-nearest-even
    uint x = __float_as_uint(f);
    x += 0x7fffu + ((x >> 16) & 1u);
    return (ushort)(x >> 16);
}
__device__ inline uint pack_bf2(float x, float y) {
    return ((uint)f2bf(y) << 16) | (uint)f2bf(x);
}
__device__ inline float bflo(uint u) { return __uint_as_float(u << 16); }
__device__ inline float bfhi(uint u) { return __uint_as_float(u & 0xffff0000u); }

// ---- build per-dst buckets: one uint per edge = f16(w)<<16 | src(16b) ------
__global__ __launch_bounds__(256) void build_k(
    const int* __restrict__ src, const int* __restrict__ dst,
    const float* __restrict__ deg,
    int* __restrict__ counts, uint* __restrict__ buck) {
    int e = blockIdx.x * 256 + threadIdx.x;   // NE % 256 == 0
    int s = __builtin_nontemporal_load(src + e);
    int v = __builtin_nontemporal_load(dst + e);
    int slot = atomicAdd(&counts[v], 1);
    if (slot < CAP) {
        float w = deg[s] * deg[v];
        buck[v * CAP + slot] = ((uint)f2h(w) << 16) | (uint)s;  // cached
    }
}

// ---- convert h (f32) -> chunk-major bf16 tables, chunk->XCD-pair affine ----
// grid 10000: c=(b&7)>>1, wi=(b>>3)*2+(b&1) in [0,2500); 2500 blocks/chunk.
__global__ __launch_bounds__(256) void cvt_k(
    const float* __restrict__ h, uint* __restrict__ tab) {
    int b   = blockIdx.x;
    int c   = (b & 7) >> 1;
    int wi  = (b >> 3) * 2 + (b & 1);
    int tgl = wi * 256 + threadIdx.x;         // u32 index within chunk
    int v = tgl >> 4, t = tgl & 15;
    f32x2 f = __builtin_nontemporal_load(
        (const f32x2*)(h + (size_t)v * 128 + c * 32 + t * 2));
    tab[(size_t)c * NN * CWU + tgl] = pack_bf2(f.x, f.y);  // cached: seeds L2
}

// ---- core gather: subgroup (16 lanes) per node; lane t owns dims 2t,2t+1 ---
__device__ inline void gather_c(
    const uint* __restrict__ tabc,            // chunk-c table, u32 units
    const int* __restrict__ counts, const uint* __restrict__ buck,
    int v, int t, float* a0, float* a1) {
    int cnt = counts[v];
    if (cnt > CAP) cnt = CAP;
    const uint* brow = buck + (size_t)v * CAP;
    float x0 = 0.f, x1 = 0.f;
    for (int j = 0; j < cnt; j += 4) {
        u32x4 bw = *(const u32x4*)(brow + j);  // broadcast in subgroup, cached
#pragma unroll
        for (int k = 0; k < 4; ++k) {
            bool ok = (j + k) < cnt;           // tail slots hold stale/poison
            uint u  = bw[k];
            float w = ok ? h2f((ushort)(u >> 16)) : 0.f;
            int   s = ok ? (int)(u & 0xffffu) : 0;
            uint  f = tabc[(size_t)s * CWU + t];   // 64 B row, L2-resident
            x0 = fmaf(w, bflo(f), x0);
            x1 = fmaf(w, bfhi(f), x1);
        }
    }
    *a0 = x0; *a1 = x1;
}

// ---- aggregation pass: chunk-affine gather -> chunk-major bf16 table -------
__global__ __launch_bounds__(256) void agg_k(
    const uint* __restrict__ tin, const int* __restrict__ counts,
    const uint* __restrict__ buck, uint* __restrict__ tout) {
    int b  = blockIdx.x;
    int c  = (b & 7) >> 1;
    int wi = (b >> 3) * 2 + (b & 1);          // [0,2500), 16 nodes per block
    int lane = threadIdx.x & 63, wave = threadIdx.x >> 6;
    int n = lane >> 4, t = lane & 15;
    int v = wi * 16 + wave * 4 + n;
    float a0, a1;
    gather_c(tin + (size_t)c * NN * CWU, counts, buck, v, t, &a0, &a1);
    // wave store: 4 consecutive node-rows x 64 B = 256 B contiguous, cached
    tout[(size_t)c * NN * CWU + (size_t)v * CWU + t] = pack_bf2(a0, a1);
}

// ---- final pass: gather P^3 chunk + alpha-combine + write 4 sections -------
__global__ __launch_bounds__(256) void agg3_k(
    const uint* __restrict__ p2t, const uint* __restrict__ p1t,
    const float* __restrict__ h, const int* __restrict__ counts,
    const uint* __restrict__ buck, const float* __restrict__ alphas,
    float* __restrict__ out) {
    int b  = blockIdx.x;
    int c  = (b & 7) >> 1;
    int wi = (b >> 3) * 2 + (b & 1);
    int lane = threadIdx.x & 63, wave = threadIdx.x >> 6;
    int n = lane >> 4, t = lane & 15;
    int v = wi * 16 + wave * 4 + n;
    float p30, p31;
    gather_c(p2t + (size_t)c * NN * CWU, counts, buck, v, t, &p30, &p31);

    float a0 = alphas[0], a1 = alphas[1], a2 = alphas[2];
    float a3 = alphas[3], a4 = alphas[4], a5 = alphas[5];
    float c1p = a0, c1h = 1.f - a0;
    float c2pp = a2 * a1;
    float c2p  = a2 * (1.f - a1) + (1.f - a2) * a1;
    float c2h  = (1.f - a2) * (1.f - a1);
    float s2pp = a4 * a3;
    float s2p  = a4 * (1.f - a3) + (1.f - a4) * a3;
    float s2h  = (1.f - a4) * (1.f - a3);
    float c3ppp = a5 * s2pp;
    float c3pp  = a5 * s2p + (1.f - a5) * s2pp;
    float c3p   = a5 * s2h + (1.f - a5) * s2p;
    float c3h   = (1.f - a5) * s2h;

    size_t idx = (size_t)c * NN * CWU + (size_t)v * CWU + t;
    uint u1 = p1t[idx], u2 = p2t[idx];        // L2-hot (same XCD pair wrote)
    float q10 = bflo(u1), q11 = bfhi(u1);
    float q20 = bflo(u2), q21 = bfhi(u2);
    f32x2 hf = __builtin_nontemporal_load(
        (const f32x2*)(h + (size_t)v * 128 + c * 32 + t * 2));

    f32x2 r1, r2, r3;
    r1.x = c1p * q10 + c1h * hf.x;
    r1.y = c1p * q11 + c1h * hf.y;
    r2.x = c2pp * q20 + c2p * q10 + c2h * hf.x;
    r2.y = c2pp * q21 + c2p * q11 + c2h * hf.y;
    r3.x = c3ppp * p30 + c3pp * q20 + c3p * q10 + c3h * hf.x;
    r3.y = c3ppp * p31 + c3pp * q21 + c3p * q11 + c3h * hf.y;

    float* o = out + (size_t)v * 512 + c * 32 + t * 2;  // 128 B per (v,sec)
    __builtin_nontemporal_store(hf, (f32x2*)(o));
    __builtin_nontemporal_store(r1, (f32x2*)(o + 128));
    __builtin_nontemporal_store(r2, (f32x2*)(o + 256));
    __builtin_nontemporal_store(r3, (f32x2*)(o + 384));
}

extern "C" void kernel_launch(void* const* d_in, const int* in_sizes, int n_in,
                              void* d_out, int out_size, void* d_ws, size_t ws_size,
                              hipStream_t stream) {
    const float* h      = (const float*)d_in[0];
    const float* deg    = (const float*)d_in[1];
    const float* alphas = (const float*)d_in[2];
    const int*   src    = (const int*)d_in[3];
    const int*   dst    = (const int*)d_in[4];
    float* out = (float*)d_out;

    // ws layout (bytes): counts 160,000 | buck 10,240,000 |
    //                    hb 10,240,000 | p1b 10,240,000 | p2b 10,240,000
    char* ws = (char*)d_ws;
    int*  counts = (int*)(ws + 0);
    uint* buck   = (uint*)(ws + 160000);
    uint* hb     = (uint*)(ws + 10400000);
    uint* p1b    = (uint*)(ws + 20640000);
    uint* p2b    = (uint*)(ws + 30880000);

    hipMemsetAsync(counts, 0, NN * sizeof(int), stream);
    build_k<<<NE / 256, 256, 0, stream>>>(src, dst, deg, counts, buck);
    cvt_k<<<NN * NCH * CWU / 256, 256, 0, stream>>>(h, hb);        // 10000

    agg_k<<<NN * NCH / 16, 256, 0, stream>>>(hb,  counts, buck, p1b);  // 10000
    agg_k<<<NN * NCH / 16, 256, 0, stream>>>(p1b, counts, buck, p2b);  // 10000
    agg3_k<<<NN * NCH / 16, 256, 0, stream>>>(p2b, p1b, h, counts, buck,
                                              alphas, out);            // 10000
}